// Round 1
// baseline (404.749 us; speedup 1.0000x reference)
//
#include <hip/hip_runtime.h>
#include <hip/hip_bf16.h>
#include <math.h>

#define N_TOK 16384
#define D_MODEL 2048
#define N_EXP 64
#define CAPACITY 640
#define BM 64
#define BK 64

// ---------------- K1: fp32 GEMM logits = x @ W^T, + z_loss partial ----------
// grid 256 blocks x 256 threads; each block: 64 tokens x 64 experts
__global__ __launch_bounds__(256) void k1_gemm(
    const float* __restrict__ x, const float* __restrict__ W,
    float* __restrict__ logits_out, float* __restrict__ z_sum) {
  __shared__ float xT[BK][BM + 4];   // [k][m]
  __shared__ float wT[BK][N_EXP + 4]; // [k][e]
  __shared__ float red[4];

  const int t = threadIdx.x;
  const int m0 = blockIdx.x * BM;
  const int ldRow = t >> 4;          // 0..15
  const int ldCol = (t & 15) * 4;    // 0..60  (k offset within tile)
  const int tr = (t >> 4) * 4;       // token sub-tile base
  const int tc = (t & 15) * 4;       // expert sub-tile base

  float acc[4][4] = {};
  float4 xr[4], wr[4];

  // prefetch first tile
#pragma unroll
  for (int i = 0; i < 4; i++) {
    xr[i] = *(const float4*)(x + (size_t)(m0 + ldRow + 16 * i) * D_MODEL + ldCol);
    wr[i] = *(const float4*)(W + (size_t)(ldRow + 16 * i) * D_MODEL + ldCol);
  }

  for (int d0 = 0; d0 < D_MODEL; d0 += BK) {
    __syncthreads();  // previous tile reads done
#pragma unroll
    for (int i = 0; i < 4; i++) {
      const int r = ldRow + 16 * i;
      xT[ldCol + 0][r] = xr[i].x; xT[ldCol + 1][r] = xr[i].y;
      xT[ldCol + 2][r] = xr[i].z; xT[ldCol + 3][r] = xr[i].w;
      wT[ldCol + 0][r] = wr[i].x; wT[ldCol + 1][r] = wr[i].y;
      wT[ldCol + 2][r] = wr[i].z; wT[ldCol + 3][r] = wr[i].w;
    }
    __syncthreads();
    const int dn = d0 + BK;
    if (dn < D_MODEL) {
#pragma unroll
      for (int i = 0; i < 4; i++) {
        xr[i] = *(const float4*)(x + (size_t)(m0 + ldRow + 16 * i) * D_MODEL + dn + ldCol);
        wr[i] = *(const float4*)(W + (size_t)(ldRow + 16 * i) * D_MODEL + dn + ldCol);
      }
    }
#pragma unroll 8
    for (int k = 0; k < BK; k++) {
      float4 a = *(const float4*)&xT[k][tr];
      float4 b = *(const float4*)&wT[k][tc];
      acc[0][0] += a.x * b.x; acc[0][1] += a.x * b.y; acc[0][2] += a.x * b.z; acc[0][3] += a.x * b.w;
      acc[1][0] += a.y * b.x; acc[1][1] += a.y * b.y; acc[1][2] += a.y * b.z; acc[1][3] += a.y * b.w;
      acc[2][0] += a.z * b.x; acc[2][1] += a.z * b.y; acc[2][2] += a.z * b.z; acc[2][3] += a.z * b.w;
      acc[3][0] += a.w * b.x; acc[3][1] += a.w * b.y; acc[3][2] += a.w * b.z; acc[3][3] += a.w * b.w;
    }
  }

  // write logits + z partial
  float zp = 0.f;
#pragma unroll
  for (int i = 0; i < 4; i++) {
    float4 v = make_float4(acc[i][0], acc[i][1], acc[i][2], acc[i][3]);
    *(float4*)(logits_out + (size_t)(m0 + tr + i) * N_EXP + tc) = v;
    zp += v.x * v.x + v.y * v.y + v.z * v.z + v.w * v.w;
  }
  const int lane = t & 63, wid = t >> 6;
#pragma unroll
  for (int off = 32; off; off >>= 1) zp += __shfl_xor(zp, off);
  if (lane == 0) red[wid] = zp;
  __syncthreads();
  if (t == 0) atomicAdd(z_sum, red[0] + red[1] + red[2] + red[3]);
}

// ---------------- K2: softmax + top2 per token (one wave each) --------------
__global__ __launch_bounds__(256) void k2_softmax(
    const float* __restrict__ logits, float* __restrict__ rw_out,
    int* __restrict__ top1, int* __restrict__ top2,
    float* __restrict__ w0p, float* __restrict__ w1p, int* __restrict__ hist) {
  const int lane = threadIdx.x & 63;
  const int n = blockIdx.x * 4 + (threadIdx.x >> 6);
  float l = logits[(size_t)n * N_EXP + lane];
  float m = l;
#pragma unroll
  for (int off = 32; off; off >>= 1) m = fmaxf(m, __shfl_xor(m, off));
  float p = __expf(l - m);
  float s = p;
#pragma unroll
  for (int off = 32; off; off >>= 1) s += __shfl_xor(s, off);
  float rw = p / s;
  rw_out[(size_t)n * N_EXP + lane] = rw;

  unsigned long long b1 = __ballot(l == m);
  int i1 = __builtin_ctzll(b1);  // lowest index on tie (matches top_k)
  float l2 = (lane == i1) ? -INFINITY : l;
  float m2 = l2;
#pragma unroll
  for (int off = 32; off; off >>= 1) m2 = fmaxf(m2, __shfl_xor(m2, off));
  unsigned long long b2 = __ballot(l == m2) & ~(1ull << i1);
  int i2 = __builtin_ctzll(b2);

  float rw1 = __shfl(rw, i1);
  float rw2 = __shfl(rw, i2);
  if (lane == 0) {
    float denom = rw1 + rw2 + 1e-8f;
    top1[n] = i1; top2[n] = i2;
    w0p[n] = rw1 / denom; w1p[n] = rw2 / denom;
    atomicAdd(&hist[i1], 1);
  }
}

// ---------------- K3: dispatch mask + per-expert counts ---------------------
__global__ __launch_bounds__(1024) void k3_dispatch(
    const int* __restrict__ top1, const int* __restrict__ top2,
    const float* __restrict__ w0p, const float* __restrict__ w1p,
    const int* __restrict__ hist, float* __restrict__ mask_out,
    float* __restrict__ counts) {
  __shared__ float cnt[N_EXP];
  const int t = threadIdx.x;
  if (t < N_EXP) cnt[t] = 0.f;
  __syncthreads();
  const int lane = t & 63;
  const int n = blockIdx.x * 16 + (t >> 6);
  const int i1 = top1[n], i2 = top2[n];
  const float w0 = w0p[n], w1 = w1p[n];
  const bool allowed = hist[i2] < CAPACITY;
  const float ssum = w0 + (allowed ? w1 : 0.f);
  const float inv = 1.f / (ssum + 1e-8f);
  float val = 0.f;
  if (lane == i1) val = w0 * inv;
  else if (allowed && lane == i2) val = w1 * inv;
  mask_out[(size_t)n * N_EXP + lane] = val;
  if (val != 0.f) atomicAdd(&cnt[lane], val);
  __syncthreads();
  if (t < N_EXP) atomicAdd(&counts[t], cnt[t]);
}

// ---------------- K4: scalar loss -------------------------------------------
__global__ void k4_loss(const float* __restrict__ counts,
                        const float* __restrict__ z_sum,
                        float* __restrict__ loss_out) {
  const int lane = threadIdx.x;
  float c = counts[lane];
  float d = (c - 512.0f) * (1.0f / 16384.0f);  // (counts - target)/N
  float v = d * d;
#pragma unroll
  for (int off = 32; off; off >>= 1) v += __shfl_xor(v, off);
  if (lane == 0) {
    float lb = v * (1.0f / 64.0f);
    float z = z_sum[0] * (1.0f / (16384.0f * 64.0f));
    loss_out[0] = 0.001f * z + 0.001f * lb;
  }
}

extern "C" void kernel_launch(void* const* d_in, const int* in_sizes, int n_in,
                              void* d_out, int out_size, void* d_ws, size_t ws_size,
                              hipStream_t stream) {
  const float* x = (const float*)d_in[0];
  const float* W = (const float*)d_in[1];
  float* out = (float*)d_out;
  float* rw_out = out;                          // N*E routing weights
  float* mask_out = out + (size_t)N_TOK * N_EXP;  // N*E dispatch mask (also logits scratch)
  float* loss_out = out + 2 * (size_t)N_TOK * N_EXP;

  char* ws = (char*)d_ws;
  int* hist = (int*)ws;                  // 64 ints
  float* counts = (float*)(ws + 256);    // 64 floats
  float* z_sum = (float*)(ws + 512);     // 1 float
  int* top1 = (int*)(ws + 1024);
  int* top2 = top1 + N_TOK;
  float* w0p = (float*)(top2 + N_TOK);
  float* w1p = w0p + N_TOK;

  hipMemsetAsync(ws, 0, 516, stream);  // hist + counts + z_sum
  k1_gemm<<<N_TOK / BM, 256, 0, stream>>>(x, W, mask_out, z_sum);
  k2_softmax<<<N_TOK / 4, 256, 0, stream>>>(mask_out, rw_out, top1, top2, w0p, w1p, hist);
  k3_dispatch<<<N_TOK / 16, 1024, 0, stream>>>(top1, top2, w0p, w1p, hist, mask_out, counts);
  k4_loss<<<1, 64, 0, stream>>>(counts, z_sum, loss_out);
}

// Round 2
// 306.126 us; speedup vs baseline: 1.3222x; 1.3222x over previous
//
#include <hip/hip_runtime.h>
#include <hip/hip_bf16.h>
#include <math.h>

#define N_TOK 16384
#define D_MODEL 2048
#define N_EXP 64
#define CAPACITY 640
#define KSPLIT 4
#define KSLICE (D_MODEL / KSPLIT)  // 512
#define BK 64
#define BM 64
#define LDP 68  // padded LDS row stride (keeps 16B alignment)

// ---------------- K1: fp32 split-K GEMM, logits += x @ W^T ------------------
// grid 1024 = 256 tiles x 4 k-slices; block 256 thr; 64 tok x 64 exp per tile
__global__ __launch_bounds__(256, 4) void k1_gemm(
    const float* __restrict__ x, const float* __restrict__ W,
    float* __restrict__ logits) {
  __shared__ float xS[BM][LDP];    // [token][k]  natural layout
  __shared__ float wS[N_EXP][LDP]; // [expert][k] natural layout

  const int t = threadIdx.x;
  const int tile = blockIdx.x & 255;
  const int ks = blockIdx.x >> 8;
  const int m0 = tile * BM;
  const int kb = ks * KSLICE;

  const int lr = t >> 4;        // loader row 0..15
  const int lc = (t & 15) * 4;  // loader col 0..60
  const int tr = t >> 4;        // token base: owns tr+16i
  const int tc = t & 15;        // expert base: owns tc+16j (strided -> bank-friendly)

  float acc[4][4] = {};
  float4 xr[4], wr[4];

  const float* xp = x + (size_t)(m0 + lr) * D_MODEL + kb + lc;
  const float* wp = W + (size_t)lr * D_MODEL + kb + lc;
#pragma unroll
  for (int i = 0; i < 4; i++) {
    xr[i] = *(const float4*)(xp + (size_t)(16 * i) * D_MODEL);
    wr[i] = *(const float4*)(wp + (size_t)(16 * i) * D_MODEL);
  }

  for (int d0 = 0; d0 < KSLICE; d0 += BK) {
    __syncthreads();
#pragma unroll
    for (int i = 0; i < 4; i++) {
      *(float4*)&xS[lr + 16 * i][lc] = xr[i];
      *(float4*)&wS[lr + 16 * i][lc] = wr[i];
    }
    __syncthreads();
    if (d0 + BK < KSLICE) {
#pragma unroll
      for (int i = 0; i < 4; i++) {
        xr[i] = *(const float4*)(xp + (size_t)(16 * i) * D_MODEL + d0 + BK);
        wr[i] = *(const float4*)(wp + (size_t)(16 * i) * D_MODEL + d0 + BK);
      }
    }
#pragma unroll 2
    for (int k4 = 0; k4 < BK; k4 += 4) {
      float4 a[4], b[4];
#pragma unroll
      for (int i = 0; i < 4; i++) a[i] = *(const float4*)&xS[tr + 16 * i][k4];
#pragma unroll
      for (int j = 0; j < 4; j++) b[j] = *(const float4*)&wS[tc + 16 * j][k4];
#pragma unroll
      for (int i = 0; i < 4; i++)
#pragma unroll
        for (int j = 0; j < 4; j++)
          acc[i][j] += a[i].x * b[j].x + a[i].y * b[j].y +
                       a[i].z * b[j].z + a[i].w * b[j].w;
    }
  }
#pragma unroll
  for (int i = 0; i < 4; i++)
#pragma unroll
    for (int j = 0; j < 4; j++)
      atomicAdd(&logits[(size_t)(m0 + tr + 16 * i) * N_EXP + tc + 16 * j],
                acc[i][j]);
}

// ---------------- K2: softmax + top2 + z-loss, thread-per-token -------------
__global__ __launch_bounds__(128) void k2_softmax(
    const float* __restrict__ logits, float* __restrict__ rw_out,
    int* __restrict__ top1, int* __restrict__ top2,
    float* __restrict__ w0p, float* __restrict__ w1p,
    int* __restrict__ hist, float* __restrict__ z_sum) {
  __shared__ int lhist[N_EXP];
  __shared__ float zred[2];
  const int t = threadIdx.x;
  if (t < N_EXP) lhist[t] = 0;
  __syncthreads();

  const int n = blockIdx.x * 128 + t;
  const float* row = logits + (size_t)n * N_EXP;
  float4 r[16];
#pragma unroll
  for (int j = 0; j < 16; j++) r[j] = *(const float4*)(row + 4 * j);

  float m1 = -INFINITY, m2 = -INFINITY;
  int i1 = 0, i2 = 0;
  float zp = 0.f;
#pragma unroll
  for (int j = 0; j < 16; j++) {
    float v[4] = {r[j].x, r[j].y, r[j].z, r[j].w};
#pragma unroll
    for (int c = 0; c < 4; c++) {
      const float vv = v[c];
      const int e = 4 * j + c;
      zp += vv * vv;
      if (vv > m1) { m2 = m1; i2 = i1; m1 = vv; i1 = e; }
      else if (vv > m2) { m2 = vv; i2 = e; }
    }
  }

  float s = 0.f;
#pragma unroll
  for (int j = 0; j < 16; j++) {
    r[j].x = __expf(r[j].x - m1); r[j].y = __expf(r[j].y - m1);
    r[j].z = __expf(r[j].z - m1); r[j].w = __expf(r[j].w - m1);
    s += r[j].x + r[j].y + r[j].z + r[j].w;
  }
  const float inv = 1.f / s;
  float* out = rw_out + (size_t)n * N_EXP;
#pragma unroll
  for (int j = 0; j < 16; j++) {
    float4 o = make_float4(r[j].x * inv, r[j].y * inv, r[j].z * inv, r[j].w * inv);
    *(float4*)(out + 4 * j) = o;
  }

  const float rw1 = inv;                    // exp(0) * inv
  const float rw2 = __expf(m2 - m1) * inv;
  const float denom = rw1 + rw2 + 1e-8f;
  top1[n] = i1; top2[n] = i2;
  w0p[n] = rw1 / denom; w1p[n] = rw2 / denom;
  atomicAdd(&lhist[i1], 1);

  // z partial: wave reduce then one global atomic per block
#pragma unroll
  for (int off = 32; off; off >>= 1) zp += __shfl_xor(zp, off);
  if ((t & 63) == 0) zred[t >> 6] = zp;
  __syncthreads();
  if (t == 0) atomicAdd(z_sum, zred[0] + zred[1]);
  if (t < N_EXP) atomicAdd(&hist[t * 16], lhist[t]);  // padded bins
}

// ---------------- K3: dispatch mask + per-expert counts ---------------------
__global__ __launch_bounds__(128) void k3_dispatch(
    const int* __restrict__ top1, const int* __restrict__ top2,
    const float* __restrict__ w0p, const float* __restrict__ w1p,
    const int* __restrict__ hist, float* __restrict__ mask_out,
    float* __restrict__ counts) {
  __shared__ float lcnt[N_EXP];
  const int t = threadIdx.x;
  if (t < N_EXP) lcnt[t] = 0.f;
  __syncthreads();

  const int n = blockIdx.x * 128 + t;
  const int i1 = top1[n], i2 = top2[n];
  const float w0 = w0p[n], w1 = w1p[n];
  const bool allowed = hist[i2 * 16] < CAPACITY;
  const float ssum = w0 + (allowed ? w1 : 0.f);
  const float inv = 1.f / (ssum + 1e-8f);
  const float v1 = w0 * inv;
  const float v2 = allowed ? w1 * inv : 0.f;

  float* out = mask_out + (size_t)n * N_EXP;
#pragma unroll
  for (int j = 0; j < 16; j++) {
    float4 o = make_float4(0.f, 0.f, 0.f, 0.f);
    const int e0 = 4 * j;
    if (i1 >= e0 && i1 < e0 + 4) (&o.x)[i1 - e0] = v1;
    if (allowed && i2 >= e0 && i2 < e0 + 4) (&o.x)[i2 - e0] = v2;  // i1 != i2
    *(float4*)(out + 4 * j) = o;
  }
  atomicAdd(&lcnt[i1], v1);
  if (allowed) atomicAdd(&lcnt[i2], v2);
  __syncthreads();
  if (t < N_EXP) atomicAdd(&counts[t * 16], lcnt[t]);  // padded bins
}

// ---------------- K4: scalar loss -------------------------------------------
__global__ void k4_loss(const float* __restrict__ counts,
                        const float* __restrict__ z_sum,
                        float* __restrict__ loss_out) {
  const int lane = threadIdx.x;
  float c = counts[lane * 16];
  float d = (c - 512.0f) * (1.0f / 16384.0f);
  float v = d * d;
#pragma unroll
  for (int off = 32; off; off >>= 1) v += __shfl_xor(v, off);
  if (lane == 0) {
    const float lb = v * (1.0f / 64.0f);
    const float z = z_sum[0] * (1.0f / (16384.0f * 64.0f));
    loss_out[0] = 0.001f * z + 0.001f * lb;
  }
}

extern "C" void kernel_launch(void* const* d_in, const int* in_sizes, int n_in,
                              void* d_out, int out_size, void* d_ws, size_t ws_size,
                              hipStream_t stream) {
  const float* x = (const float*)d_in[0];
  const float* W = (const float*)d_in[1];
  float* out = (float*)d_out;
  float* rw_out = out;                             // [N,E] routing weights
  float* mask_out = out + (size_t)N_TOK * N_EXP;   // [N,E] mask (logits accum first)
  float* loss_out = out + 2 * (size_t)N_TOK * N_EXP;

  char* ws = (char*)d_ws;
  int* hist = (int*)ws;                      // 64 bins, stride 16 (4 KB)
  float* counts = (float*)(ws + 4096);       // 64 bins, stride 16 (4 KB)
  float* z_sum = (float*)(ws + 8192);        // 1 float
  int* top1 = (int*)(ws + 12288);
  int* top2 = top1 + N_TOK;
  float* w0p = (float*)(top2 + N_TOK);
  float* w1p = w0p + N_TOK;

  hipMemsetAsync(ws, 0, 8192 + 256, stream);                       // hist/counts/z
  hipMemsetAsync(mask_out, 0, (size_t)N_TOK * N_EXP * 4, stream);  // logits accum
  k1_gemm<<<256 * KSPLIT, 256, 0, stream>>>(x, W, mask_out);
  k2_softmax<<<N_TOK / 128, 128, 0, stream>>>(mask_out, rw_out, top1, top2,
                                              w0p, w1p, hist, z_sum);
  k3_dispatch<<<N_TOK / 128, 128, 0, stream>>>(top1, top2, w0p, w1p, hist,
                                               mask_out, counts);
  k4_loss<<<1, 64, 0, stream>>>(counts, z_sum, loss_out);
}